// Round 16
// baseline (606.351 us; speedup 1.0000x reference)
//
#include <hip/hip_runtime.h>
#include <hip/hip_bf16.h>

// Spikformer block on MI355X.
// Fast path: exact bf16-split MFMA GEMMs (fp32 = 3 bf16 planes; 6 products for
// fp32 x fp32, 3 products for binary-spike x fp32) + fused LN+LIF + exact
// sparse spike-attention (0.125 * q @ (k^T @ v), integer counts).
// R16 (= R14 resubmit; container died twice): gemm256 deep prefetch via
// region-granular buffer recycling — tile t phase 3/4 stages T(t+2) into buf
// p's dead A/B regions (gray-code consumed them into registers). 2 waits/tile:
// vmcnt(10) at start, vmcnt(8) at phase 3; 5-6 phase flight windows.
// proj/fc2 split-K x2 (R12), lnlif2/attention (R8).
// Fallback path (ws_size too small): round-2 fp32 VALU pipeline (verified).

#define NB 4
#define LL 1024
#define DIM 1024
#define NH 16
#define HDIM 64
#define HID 4096
#define NROWS (NB * LL)

typedef unsigned short u16;
typedef __attribute__((ext_vector_type(8))) short short8v;   // 8 bf16 (4 VGPRs)
typedef __attribute__((ext_vector_type(4))) float f32x4;     // MFMA acc

// ---------------- bf16 split helpers (RNE; split is exact by construction) ---
__device__ __forceinline__ u16 f2bf(float f) {
    unsigned u = __builtin_bit_cast(unsigned, f);
    return (u16)((u + 0x7fffu + ((u >> 16) & 1u)) >> 16);
}
__device__ __forceinline__ float bf2f(u16 h) {
    unsigned u = ((unsigned)h) << 16;
    return __builtin_bit_cast(float, u);
}
__device__ __forceinline__ void split3v(float v, u16& a, u16& b, u16& c) {
    a = f2bf(v);
    float r = v - bf2f(a);
    b = f2bf(r);
    float r2 = r - bf2f(b);
    c = f2bf(r2);
}

// ---------------- split x (f32 [M][K]) -> planes bf16 [M][3K] ----------------
__global__ __launch_bounds__(256) void split3_rows(
    const float* __restrict__ X, u16* __restrict__ Xs, int K)
{
    const int row = blockIdx.y;
    const int c4 = (blockIdx.x * 256 + threadIdx.x) * 4;
    if (c4 >= K) return;
    float4 v = *(const float4*)(X + (size_t)row * K + c4);
    float vv[4] = {v.x, v.y, v.z, v.w};
    u16 h0[4], h1[4], h2[4];
#pragma unroll
    for (int j = 0; j < 4; ++j) split3v(vv[j], h0[j], h1[j], h2[j]);
    u16* base = Xs + (size_t)row * 3 * K + c4;
    *(uint2*)(base + 0 * K) = *(uint2*)h0;
    *(uint2*)(base + 1 * K) = *(uint2*)h1;
    *(uint2*)(base + 2 * K) = *(uint2*)h2;
}

// ------------- split + transpose W (f32 [K][N]) -> Wt bf16 [N][3K] -----------
__global__ __launch_bounds__(256) void split_wt(
    const float* __restrict__ W, u16* __restrict__ Wt, int K, int N, int ldwt)
{
    __shared__ float tile[64][65];   // [n][k], padded
    const int k0 = blockIdx.y * 64, n0 = blockIdx.x * 64;
    const int t = threadIdx.x;
    const int rr = t >> 4;            // 0..15 (k within chunk)
    const int cc = (t & 15) * 4;      // 0..60 (n)
#pragma unroll
    for (int it = 0; it < 4; ++it) {
        const int k = rr + it * 16;
        float4 v = *(const float4*)(W + (size_t)(k0 + k) * N + n0 + cc);
        tile[cc + 0][k] = v.x; tile[cc + 1][k] = v.y;
        tile[cc + 2][k] = v.z; tile[cc + 3][k] = v.w;
    }
    __syncthreads();
    const int n = t >> 2, kc = (t & 3) * 16;
    u16 h0[16], h1[16], h2[16];
#pragma unroll
    for (int j = 0; j < 16; ++j)
        split3v(tile[n][kc + j], h0[j], h1[j], h2[j]);
    u16* base = Wt + (size_t)(n0 + n) * ldwt + k0 + kc;
    *(uint4*)(base + 0 * K)     = ((uint4*)h0)[0];
    *(uint4*)(base + 0 * K + 8) = ((uint4*)h0)[1];
    *(uint4*)(base + 1 * K)     = ((uint4*)h1)[0];
    *(uint4*)(base + 1 * K + 8) = ((uint4*)h1)[1];
    *(uint4*)(base + 2 * K)     = ((uint4*)h2)[0];
    *(uint4*)(base + 2 * K + 8) = ((uint4*)h2)[1];
}

#define AS1G const __attribute__((address_space(1))) void*
#define AS3L __attribute__((address_space(3))) void*

// ============ 256^2 8-wave GEMM, deep-prefetch counted vmcnt ================
// Kseg=1024 per seg, BK=64, nt K-tiles; seg plane ids packed 4-bit in
// apack/bpack (column offset = plane*1024 + (tile&15)*64).
// A bf16 [M][lda] row-major; Bt bf16 [N][ldb] (k contiguous per output col).
// LDS 128KB: 2 buf x (A 32KB + B 32KB).  A LDS row = tile row (identity).
// B LDS row rho <-> global col: c(rho) = ((rho>>5)&3)*64 + (rho>>7)*32 + (rho&31).
// 16B-slot swizzle: LDS slot s of row r holds logical slot s^(r&7).
// Gray-code quadrants (0,0)->(1,0)->(1,1)->(0,1), persistent operand regs.
// Region recycling: after phase 2 all of buf p's A is in registers; after
// phase 3 all of B. Phase 3 stages T(t+2).A into p.A, phase 4 T(t+2).B into
// p.B. FIFO [T+1.A x4, T+1.B x4, T+2.A x4, T+2.B x4] -> waits vmcnt(10) at
// tile start (covers phases 1+2) and vmcnt(8) at phase 3. Last tile: 2 -> 0.
__global__ __launch_bounds__(512, 2) void gemm256(
    const u16* __restrict__ A, int lda,
    const u16* __restrict__ Bt, int ldb,
    unsigned apack, unsigned bpack, int nt,
    const float* __restrict__ bias,
    float* __restrict__ Out, int ldo)
{
    __shared__ u16 As2[2][16384];
    __shared__ u16 Bs2[2][16384];
    const int t = threadIdx.x;
    const int wid = t >> 6, lane = t & 63;
    const int wm = wid >> 2, wn = wid & 3;          // 2 x 4 wave grid
    // XCD-aware tile swizzle (bijective: nwg is a multiple of 8)
    int bid = blockIdx.y * gridDim.x + blockIdx.x;
    const int nwg = gridDim.x * gridDim.y;
    bid = (bid & 7) * (nwg >> 3) + (bid >> 3);
    const int row0 = (bid / gridDim.x) * 256, col0 = (bid % gridDim.x) * 256;
    const int lrow = lane & 15, lk = lane >> 4;
    const int sr0 = t >> 3;                         // 0..63 row in stage region
    const int scol = ((t & 7) ^ (sr0 & 7)) * 8;     // pre-swizzled source slot

    f32x4 acc[8][4];
#pragma unroll
    for (int i = 0; i < 8; ++i)
#pragma unroll
        for (int j = 0; j < 4; ++j) acc[i][j] = f32x4{0.f, 0.f, 0.f, 0.f};
    short8v afA[4][2], afB[4][2], bf[2][2];         // persistent operand regs

#define STA(bs, Rb, c0)                                                        \
    __builtin_amdgcn_global_load_lds(                                          \
        (AS1G)(A + (size_t)(row0 + (Rb) + sr0) * lda + (c0) + scol),           \
        (AS3L)(&As2[bs][(Rb) * 64 + t * 8]), 16, 0, 0);
#define STB(bs, Rb, c0)                                                        \
    {                                                                          \
        const int _rho = (Rb) + sr0;                                           \
        const int _bc = ((_rho >> 5) & 3) * 64 + ((_rho >> 7) << 5) + (_rho & 31); \
        __builtin_amdgcn_global_load_lds(                                      \
            (AS1G)(Bt + (size_t)(col0 + _bc) * ldb + (c0) + scol),             \
            (AS3L)(&Bs2[bs][(Rb) * 64 + t * 8]), 16, 0, 0);                    \
    }
// FIFO groups: A-group (all 4 A loads), B-group (NQ0 rows first, then NQ1)
#define STAGE_A(bs, cA) STA(bs, 0, cA) STA(bs, 128, cA) STA(bs, 64, cA) STA(bs, 192, cA)
#define STAGE_B(bs, cB) STB(bs, 0, cB) STB(bs, 64, cB) STB(bs, 128, cB) STB(bs, 192, cB)

#define VMW(n) asm volatile("s_waitcnt vmcnt(" #n ")" ::: "memory");
#define BAR  __builtin_amdgcn_s_barrier();
#define BARP                                                                   \
    __builtin_amdgcn_s_barrier();                                              \
    __builtin_amdgcn_sched_barrier(0);

#define LDA(dst, MQ, P)                                                        \
    _Pragma("unroll")                                                          \
    for (int mf = 0; mf < 4; ++mf) {                                           \
        const int r = wm * 128 + (MQ) * 64 + mf * 16 + lrow;                   \
        _Pragma("unroll")                                                      \
        for (int ks = 0; ks < 2; ++ks) {                                       \
            const int slot = (lk + ks * 4) ^ (r & 7);                          \
            dst[mf][ks] = *(const short8v*)&As2[P][r * 64 + slot * 8];         \
        }                                                                      \
    }
#define LDB(NQ, P)                                                             \
    _Pragma("unroll")                                                          \
    for (int nf = 0; nf < 2; ++nf) {                                           \
        const int rho = (NQ) * 128 + (wn >> 1) * 64 + (wn & 1) * 32            \
                        + nf * 16 + lrow;                                      \
        _Pragma("unroll")                                                      \
        for (int ks = 0; ks < 2; ++ks) {                                       \
            const int slot = (lk + ks * 4) ^ (rho & 7);                        \
            bf[nf][ks] = *(const short8v*)&Bs2[P][rho * 64 + slot * 8];        \
        }                                                                      \
    }
#define MM(asrc, MQ, NQ)                                                       \
    __builtin_amdgcn_s_setprio(1);                                             \
    _Pragma("unroll")                                                          \
    for (int mf = 0; mf < 4; ++mf)                                             \
        _Pragma("unroll")                                                      \
        for (int nf = 0; nf < 2; ++nf)                                         \
            _Pragma("unroll")                                                  \
            for (int ks = 0; ks < 2; ++ks)                                     \
                acc[(MQ) * 4 + mf][(NQ) * 2 + nf] =                            \
                    __builtin_amdgcn_mfma_f32_16x16x32_bf16(                   \
                        asrc[mf][ks], bf[nf][ks],                              \
                        acc[(MQ) * 4 + mf][(NQ) * 2 + nf], 0, 0, 0);           \
    __builtin_amdgcn_s_setprio(0);

    // prologue: stage T0 -> buf0 and T1 -> buf1 (A-group then B-group each).
    {
        const int cA0 = (apack & 15) * 1024;
        const int cB0 = (bpack & 15) * 1024;
        STAGE_A(0, cA0) STAGE_B(0, cB0)
        const int cA1 = (apack & 15) * 1024 + 64;   // tile 1: nns=0, nk0=64
        const int cB1 = (bpack & 15) * 1024 + 64;
        STAGE_A(1, cA1) STAGE_B(1, cB1)
    }

    // main tiles 0..nt-2: waits vmcnt(10)/vmcnt(8); phase 3/4 stage T(t+2)
    // into buf p's dead A/B regions.
    for (int kt = 0; kt < nt - 1; ++kt) {
        const int p = kt & 1;
        const int fkt = kt + 2;
        const bool more2 = fkt < nt;
        int fA = 0, fB = 0;
        if (more2) {
            const int fns = fkt >> 4, fk0 = (fkt & 15) * 64;
            fA = (int)((apack >> (fns * 4)) & 15) * 1024 + fk0;
            fB = (int)((bpack >> (fns * 4)) & 15) * 1024 + fk0;
        }
        VMW(10) BARP                       // T(t).A + T(t).B-NQ0 landed
        LDA(afA, 0, p) LDB(0, p) MM(afA, 0, 0)
        BAR                                 // (T(t).A fully covered by vmcnt(10))
        LDA(afB, 1, p) MM(afB, 1, 0)
        VMW(8) BAR                          // T(t).B-NQ1 landed; p.A now dead
        LDB(1, p)
        if (more2) { STAGE_A(p, fA) }
        MM(afB, 1, 1)
        BAR                                 // p.B now dead
        if (more2) { STAGE_B(p, fB) }
        MM(afA, 0, 1)
    }
    // last tile: only its own 8 loads outstanding -> waits 2 then 0.
    {
        const int p = (nt - 1) & 1;
        VMW(2) BARP LDA(afA, 0, p) LDB(0, p) MM(afA, 0, 0)
        BAR         LDA(afB, 1, p) MM(afB, 1, 0)
        VMW(0) BAR  LDB(1, p) MM(afB, 1, 1)
        BAR         MM(afA, 0, 1)
    }
#undef STAGE_A
#undef STAGE_B
#undef LDA
#undef LDB
#undef MM

    // epilogue: C/D layout col=lane&15, row=(lane>>4)*4+reg  [m89-verified]
#pragma unroll
    for (int ni = 0; ni < 4; ++ni) {
        const int col = col0 + wn * 64 + ni * 16 + lrow;
        const float bv = bias ? bias[col] : 0.f;
#pragma unroll
        for (int mi = 0; mi < 8; ++mi) {
            const int rbase = row0 + wm * 128 + mi * 16 + lk * 4;
#pragma unroll
            for (int r = 0; r < 4; ++r)
                Out[(size_t)(rbase + r) * ldo + col] = acc[mi][ni][r] + bv;
        }
    }
#undef STA
#undef STB
#undef VMW
#undef BAR
#undef BARP
}

// ---------------- 128^2 MFMA GEMM (verified 2-barrier) with split-K ----------
// blockIdx.z selects a K-half: seg offsets shifted by z*Kseg, output written to
// partial buffer z (Out + z * M * ldo). Bias added only in z == 0.
struct SegList { int a[6]; int b[6]; int n; };

template <int BN_>
__global__ __launch_bounds__(256) void gemm_mfma(
    const u16* __restrict__ A, int lda,
    const u16* __restrict__ Bt, int ldb,
    SegList segs, int Kseg,
    const float* __restrict__ bias,
    float* __restrict__ Out, int ldo)
{
    constexpr int NF = BN_ / 32;              // B-frags per wave (2 or 4)
    __shared__ u16 As[128 * 64];              // 16 KB
    __shared__ u16 Bs[BN_ * 64];              // 8/16 KB
    const int t = threadIdx.x;
    const int wid = t >> 6, lane = t & 63;
    const int wr = wid >> 1, wc = wid & 1;
    const int z = blockIdx.z;
    const int koff = z * Kseg;
    Out += (size_t)z * (size_t)gridDim.y * 128 * ldo;
    // XCD-aware tile swizzle (bijective: nwg is a multiple of 8)
    int bid = blockIdx.y * gridDim.x + blockIdx.x;
    const int nwg = gridDim.x * gridDim.y;
    bid = (bid & 7) * (nwg >> 3) + (bid >> 3);
    const int row0 = (bid / gridDim.x) * 128, col0 = (bid % gridDim.x) * BN_;
    const int lrow = lane & 15;
    const int s_subrow = lane >> 3;                       // 0..7
    const int s_slot   = (lane & 7) ^ (lane >> 3);        // pre-swizzled slot
    const int s_coff   = s_slot * 8;

    f32x4 acc[4][NF];
#pragma unroll
    for (int i = 0; i < 4; ++i)
#pragma unroll
        for (int j = 0; j < NF; ++j) acc[i][j] = f32x4{0.f, 0.f, 0.f, 0.f};

    for (int s = 0; s < segs.n; ++s) {
        const u16* pa = A + segs.a[s] + koff;
        const u16* pb = Bt + segs.b[s] + koff;
        for (int k0 = 0; k0 < Kseg; k0 += 64) {
            asm volatile("s_waitcnt lgkmcnt(0)" ::: "memory");
            __syncthreads();
#pragma unroll
            for (int c = 0; c < 4; ++c) {          // A tile: 16 chunks, 4/wave
                const int chunk = wid * 4 + c;
                const int rg = row0 + chunk * 8 + s_subrow;
                __builtin_amdgcn_global_load_lds(
                    (AS1G)(pa + (size_t)rg * lda + k0 + s_coff),
                    (AS3L)(&As[chunk * 512 + lane * 8]), 16, 0, 0);
            }
#pragma unroll
            for (int c = 0; c < NF; ++c) {         // B tile
                const int chunk = wid * NF + c;
                const int rg = col0 + chunk * 8 + s_subrow;
                __builtin_amdgcn_global_load_lds(
                    (AS1G)(pb + (size_t)rg * ldb + k0 + s_coff),
                    (AS3L)(&Bs[chunk * 512 + lane * 8]), 16, 0, 0);
            }
            asm volatile("s_waitcnt vmcnt(0)" ::: "memory");
            __syncthreads();
#pragma unroll
            for (int ksub = 0; ksub < 2; ++ksub) {
                short8v af[4], bfr[NF];
#pragma unroll
                for (int f = 0; f < 4; ++f) {
                    const int ra = wr * 64 + f * 16 + lrow;
                    const int slot = ((lane >> 4) + ksub * 4) ^ (lrow & 7);
                    af[f] = *(const short8v*)&As[ra * 64 + slot * 8];
                }
#pragma unroll
                for (int f = 0; f < NF; ++f) {
                    const int rb = wc * (BN_ / 2) + f * 16 + lrow;
                    const int slot = ((lane >> 4) + ksub * 4) ^ (lrow & 7);
                    bfr[f] = *(const short8v*)&Bs[rb * 64 + slot * 8];
                }
#pragma unroll
                for (int i = 0; i < 4; ++i)
#pragma unroll
                    for (int j = 0; j < NF; ++j)
                        acc[i][j] = __builtin_amdgcn_mfma_f32_16x16x32_bf16(
                            af[i], bfr[j], acc[i][j], 0, 0, 0);
            }
        }
    }
#pragma unroll
    for (int j = 0; j < NF; ++j) {
        const int col = col0 + wc * (BN_ / 2) + j * 16 + lrow;
        const float bv = (bias && z == 0) ? bias[col] : 0.f;
#pragma unroll
        for (int i = 0; i < 4; ++i) {
            const int rbase = row0 + wr * 64 + i * 16 + (lane >> 4) * 4;
#pragma unroll
            for (int r = 0; r < 4; ++r)
                Out[(size_t)(rbase + r) * ldo + col] = acc[i][j][r] + bv;
        }
    }
}

// ---------------- fused LN + LIF, multi-output (float4-vectorized) ----------
// Optional U2: second partial buffer summed on load (split-K reduce).
template <int DN>
__global__ __launch_bounds__(256) void lnlif2(
    const float* __restrict__ U, const float* __restrict__ U2, int ld, int coloff,
    const float* __restrict__ g, const float* __restrict__ beta,
    const float* __restrict__ resid,
    u16* __restrict__ spike_bf16,
    float* __restrict__ out_f32,
    u16* __restrict__ split3_out)
{
    constexpr int PT = DN / 1024;    // float4s per thread (1 for 1024, 4 for 4096)
    const int r = blockIdx.x, t = threadIdx.x;
    const float4* u4 = (const float4*)(U + (size_t)r * ld + coloff);
    const float4* u24 = U2 ? (const float4*)(U2 + (size_t)r * ld + coloff) : nullptr;
    float4 vals[PT];
    float lsum = 0.f;
#pragma unroll
    for (int i = 0; i < PT; ++i) {
        vals[i] = u4[t + i * 256];
        if (u24) {
            float4 w = u24[t + i * 256];
            vals[i].x += w.x; vals[i].y += w.y;
            vals[i].z += w.z; vals[i].w += w.w;
        }
        lsum += (vals[i].x + vals[i].y) + (vals[i].z + vals[i].w);
    }
    __shared__ float red[4];
    __shared__ float bcast;
    for (int o = 32; o > 0; o >>= 1) lsum += __shfl_down(lsum, o);
    if ((t & 63) == 0) red[t >> 6] = lsum;
    __syncthreads();
    if (t == 0) bcast = (red[0] + red[1] + red[2] + red[3]) * (1.f / DN);
    __syncthreads();
    const float m = bcast;
    float lss = 0.f;
#pragma unroll
    for (int i = 0; i < PT; ++i) {
        float dx = vals[i].x - m, dy = vals[i].y - m;
        float dz = vals[i].z - m, dw = vals[i].w - m;
        lss += (dx * dx + dy * dy) + (dz * dz + dw * dw);
    }
    for (int o = 32; o > 0; o >>= 1) lss += __shfl_down(lss, o);
    if ((t & 63) == 0) red[t >> 6] = lss;
    __syncthreads();
    if (t == 0) bcast = (red[0] + red[1] + red[2] + red[3]) * (1.f / DN);
    __syncthreads();
    const float rs = 1.f / sqrtf(bcast + 1e-5f);
#pragma unroll
    for (int i = 0; i < PT; ++i) {
        const int c = (t + i * 256) * 4;
        const size_t idx = (size_t)r * DN + c;
        const float4 gg = *(const float4*)(g + c);
        const float4 bb = *(const float4*)(beta + c);
        float sv[4];
        sv[0] = ((vals[i].x - m) * rs * gg.x + bb.x >= 2.0f) ? 1.f : 0.f;
        sv[1] = ((vals[i].y - m) * rs * gg.y + bb.y >= 2.0f) ? 1.f : 0.f;
        sv[2] = ((vals[i].z - m) * rs * gg.z + bb.z >= 2.0f) ? 1.f : 0.f;
        sv[3] = ((vals[i].w - m) * rs * gg.w + bb.w >= 2.0f) ? 1.f : 0.f;
        if (spike_bf16) {
            u16 sp[4];
#pragma unroll
            for (int j = 0; j < 4; ++j) sp[j] = sv[j] != 0.f ? (u16)0x3F80 : (u16)0;
            *(uint2*)(spike_bf16 + idx) = *(uint2*)sp;
        }
        if (out_f32 || split3_out) {
            float4 rv = resid ? *(const float4*)(resid + idx)
                              : float4{0.f, 0.f, 0.f, 0.f};
            float vv[4] = {rv.x + sv[0], rv.y + sv[1], rv.z + sv[2], rv.w + sv[3]};
            if (out_f32) {
                float4 ov = {vv[0], vv[1], vv[2], vv[3]};
                *(float4*)(out_f32 + idx) = ov;
            }
            if (split3_out) {
                u16 h0[4], h1[4], h2[4];
#pragma unroll
                for (int j = 0; j < 4; ++j) split3v(vv[j], h0[j], h1[j], h2[j]);
                u16* base = split3_out + (size_t)r * 3 * DN + c;
                *(uint2*)(base + 0 * DN) = *(uint2*)h0;
                *(uint2*)(base + 1 * DN) = *(uint2*)h1;
                *(uint2*)(base + 2 * DN) = *(uint2*)h2;
            }
        }
    }
}

// ------- attention: ktv partials (split L into 4 chunks; exact counts) -------
__global__ __launch_bounds__(256) void ktv_part(
    const u16* __restrict__ Sk, const u16* __restrict__ Sv,
    float* __restrict__ ktvp)
{
    const int bh = blockIdx.x, ck = blockIdx.y;    // ck: L-chunk 0..3
    const int b = bh >> 4, h = bh & 15;
    __shared__ float kch[64][64];
    __shared__ float vch[64][64];
    const int t = threadIdx.x;
    const int i = t >> 2;
    const int j0 = (t & 3) << 4;
    float4 a0 = {0,0,0,0}, a1 = {0,0,0,0}, a2 = {0,0,0,0}, a3 = {0,0,0,0};
    for (int l0 = ck * 256; l0 < ck * 256 + 256; l0 += 64) {
        __syncthreads();
#pragma unroll
        for (int q = 0; q < 2; ++q) {
            const int chunk = t + q * 256;
            const int li = chunk >> 3, c8 = (chunk & 7) << 3;
            const size_t off = ((size_t)b * LL + l0 + li) * DIM + h * HDIM + c8;
            union { uint4 v; u16 s[8]; } uk, uv;
            uk.v = *(const uint4*)(Sk + off);
            uv.v = *(const uint4*)(Sv + off);
#pragma unroll
            for (int j = 0; j < 8; ++j) {
                kch[li][c8 + j] = uk.s[j] ? 1.f : 0.f;
                vch[li][c8 + j] = uv.s[j] ? 1.f : 0.f;
            }
        }
        __syncthreads();
        for (int l = 0; l < 64; ++l) {
            if (kch[l][i] != 0.f) {
                const float4 v0 = *(float4*)&vch[l][j0];
                const float4 v1 = *(float4*)&vch[l][j0 + 4];
                const float4 v2 = *(float4*)&vch[l][j0 + 8];
                const float4 v3 = *(float4*)&vch[l][j0 + 12];
                a0.x += v0.x; a0.y += v0.y; a0.z += v0.z; a0.w += v0.w;
                a1.x += v1.x; a1.y += v1.y; a1.z += v1.z; a1.w += v1.w;
                a2.x += v2.x; a2.y += v2.y; a2.z += v2.z; a2.w += v2.w;
                a3.x += v3.x; a3.y += v3.y; a3.z += v3.z; a3.w += v3.w;
            }
        }
    }
    const size_t o = (((size_t)ck * 64 + bh) * 64 + i) * 64 + j0;
    *(float4*)(ktvp + o)      = a0;
    *(float4*)(ktvp + o + 4)  = a1;
    *(float4*)(ktvp + o + 8)  = a2;
    *(float4*)(ktvp + o + 12) = a3;
}

// --- attention: q@(ktv), LIF(v_th=0.5); sums 4 partials (fixed order, exact) --
__global__ __launch_bounds__(256) void qktv_bf16(
    const u16* __restrict__ Sq, const float* __restrict__ ktvp,
    u16* __restrict__ Y)
{
    const int bh = blockIdx.x, ck = blockIdx.y;    // ck: row-chunk 0..7
    const int b = bh >> 4, h = bh & 15;
    __shared__ float kt[64][64];
    const int t = threadIdx.x;
#pragma unroll
    for (int q = 0; q < 16; ++q) {
        const int idx = t + q * 256;
        ((float*)kt)[idx] = (ktvp[((size_t)0 * 64 + bh) * 4096 + idx]
                           + ktvp[((size_t)1 * 64 + bh) * 4096 + idx])
                          + (ktvp[((size_t)2 * 64 + bh) * 4096 + idx]
                           + ktvp[((size_t)3 * 64 + bh) * 4096 + idx]);
    }
    __syncthreads();
    const int li = t >> 6;
    const int j = t & 63;
    for (int l0 = ck * 128; l0 < ck * 128 + 128; l0 += 4) {
        const size_t roff = ((size_t)b * LL + l0 + li) * DIM + h * HDIM;
        const u16 sqv = Sq[roff + j];
        unsigned long long mask = __ballot(sqv != 0);
        float acc = 0.f;
        while (mask) {
            const int i = __ffsll((unsigned long long)mask) - 1;
            mask &= mask - 1;
            acc += kt[i][j];
        }
        const float y = 0.125f * acc;
        Y[roff + j] = (y >= 1.0f) ? (u16)0x3F80 : (u16)0;
    }
}

// ======================= FALLBACK (round-2 fp32 path) ========================
#define BM 128
#define BN 128
#define BK 16

__global__ __launch_bounds__(256) void gemm_f32(
    const float* __restrict__ A, const float* __restrict__ W,
    const float* __restrict__ bias, float* __restrict__ U,
    int M, int K, int N)
{
    __shared__ float As[BK][BM];
    __shared__ float Bs[BK][BN];
    const int t = threadIdx.x;
    const int tx = t & 15, ty = t >> 4;
    const int row0 = blockIdx.y * BM, col0 = blockIdx.x * BN;
    const int ar = t >> 2;
    const int ac = (t & 3) << 2;
    const int br = t >> 5;
    const int bc = (t & 31) << 2;
    float acc[8][8];
#pragma unroll
    for (int i = 0; i < 8; ++i)
#pragma unroll
        for (int j = 0; j < 8; ++j) acc[i][j] = 0.f;
    for (int k0 = 0; k0 < K; k0 += BK) {
        float4 va0 = *(const float4*)(A + (size_t)(row0 + ar) * K + k0 + ac);
        float4 va1 = *(const float4*)(A + (size_t)(row0 + ar + 64) * K + k0 + ac);
        float4 vb0 = *(const float4*)(W + (size_t)(k0 + br) * N + col0 + bc);
        float4 vb1 = *(const float4*)(W + (size_t)(k0 + br + 8) * N + col0 + bc);
        __syncthreads();
        As[ac + 0][ar] = va0.x; As[ac + 1][ar] = va0.y;
        As[ac + 2][ar] = va0.z; As[ac + 3][ar] = va0.w;
        As[ac + 0][ar + 64] = va1.x; As[ac + 1][ar + 64] = va1.y;
        As[ac + 2][ar + 64] = va1.z; As[ac + 3][ar + 64] = va1.w;
        *(float4*)&Bs[br][bc] = vb0;
        *(float4*)&Bs[br + 8][bc] = vb1;
        __syncthreads();
#pragma unroll
        for (int kk = 0; kk < BK; ++kk) {
            float4 fa0 = *(float4*)&As[kk][ty * 8];
            float4 fa1 = *(float4*)&As[kk][ty * 8 + 4];
            float4 fb0 = *(float4*)&Bs[kk][tx * 8];
            float4 fb1 = *(float4*)&Bs[kk][tx * 8 + 4];
            float av[8] = {fa0.x, fa0.y, fa0.z, fa0.w, fa1.x, fa1.y, fa1.z, fa1.w};
            float bv[8] = {fb0.x, fb0.y, fb0.z, fb0.w, fb1.x, fb1.y, fb1.z, fb1.w};
#pragma unroll
            for (int i = 0; i < 8; ++i)
#pragma unroll
                for (int j = 0; j < 8; ++j)
                    acc[i][j] += av[i] * bv[j];
        }
    }
    float bvals[8];
#pragma unroll
    for (int j = 0; j < 8; ++j)
        bvals[j] = bias ? bias[col0 + tx * 8 + j] : 0.f;
#pragma unroll
    for (int i = 0; i < 8; ++i) {
        const int row = row0 + ty * 8 + i;
        float* dst = U + (size_t)row * N + col0 + tx * 8;
        float4 o0, o1;
        o0.x = acc[i][0] + bvals[0]; o0.y = acc[i][1] + bvals[1];
        o0.z = acc[i][2] + bvals[2]; o0.w = acc[i][3] + bvals[3];
        o1.x = acc[i][4] + bvals[4]; o1.y = acc[i][5] + bvals[5];
        o1.z = acc[i][6] + bvals[6]; o1.w = acc[i][7] + bvals[7];
        *(float4*)dst = o0;
        *(float4*)(dst + 4) = o1;
    }
}

template <int DN>
__global__ __launch_bounds__(256) void lnlif_old(
    const float* __restrict__ U, const float* __restrict__ g,
    const float* __restrict__ beta, float thr,
    const float* __restrict__ resid, float* __restrict__ out)
{
    constexpr int PT = DN / 256;
    const int r = blockIdx.x, t = threadIdx.x;
    const float* u = U + (size_t)r * DN;
    float vals[PT];
    float lsum = 0.f;
#pragma unroll
    for (int i = 0; i < PT; ++i) { vals[i] = u[t + i * 256]; lsum += vals[i]; }
    __shared__ float red[4];
    __shared__ float bc0;
    for (int o = 32; o > 0; o >>= 1) lsum += __shfl_down(lsum, o);
    if ((t & 63) == 0) red[t >> 6] = lsum;
    __syncthreads();
    if (t == 0) bc0 = (red[0] + red[1] + red[2] + red[3]) * (1.f / DN);
    __syncthreads();
    const float m = bc0;
    float lss = 0.f;
#pragma unroll
    for (int i = 0; i < PT; ++i) { float d = vals[i] - m; lss += d * d; }
    for (int o = 32; o > 0; o >>= 1) lss += __shfl_down(lss, o);
    if ((t & 63) == 0) red[t >> 6] = lss;
    __syncthreads();
    if (t == 0) bc0 = (red[0] + red[1] + red[2] + red[3]) * (1.f / DN);
    __syncthreads();
    const float rs = 1.0f / sqrtf(bc0 + 1e-5f);
#pragma unroll
    for (int i = 0; i < PT; ++i) {
        const int c = t + i * 256;
        const float nrm = (vals[i] - m) * rs * g[c] + beta[c];
        const float s = (nrm >= thr) ? 1.0f : 0.0f;
        out[(size_t)r * DN + c] = resid ? (resid[(size_t)r * DN + c] + s) : s;
    }
}

__global__ __launch_bounds__(256) void ktv_f32(
    const float* __restrict__ Sk, const float* __restrict__ Sv,
    float* __restrict__ ktvb)
{
    const int bh = blockIdx.x;
    const int b = bh >> 4, h = bh & 15;
    __shared__ float kch[64][64];
    __shared__ float vch[64][64];
    const int t = threadIdx.x;
    const int i = t >> 2;
    const int j0 = (t & 3) << 4;
    float4 a0 = {0,0,0,0}, a1 = {0,0,0,0}, a2 = {0,0,0,0}, a3 = {0,0,0,0};
    for (int l0 = 0; l0 < LL; l0 += 64) {
        __syncthreads();
#pragma unroll
        for (int q = 0; q < 4; ++q) {
            const int idx = t + q * 256;
            const int li = idx >> 4, c4 = (idx & 15) << 2;
            const size_t off = ((size_t)b * LL + l0 + li) * DIM + h * HDIM + c4;
            *(float4*)&kch[li][c4] = *(const float4*)(Sk + off);
            *(float4*)&vch[li][c4] = *(const float4*)(Sv + off);
        }
        __syncthreads();
        for (int l = 0; l < 64; ++l) {
            if (kch[l][i] != 0.f) {
                const float4 v0 = *(float4*)&vch[l][j0];
                const float4 v1 = *(float4*)&vch[l][j0 + 4];
                const float4 v2 = *(float4*)&vch[l][j0 + 8];
                const float4 v3 = *(float4*)&vch[l][j0 + 12];
                a0.x += v0.x; a0.y += v0.y; a0.z += v0.z; a0.w += v0.w;
                a1.x += v1.x; a1.y += v1.y; a1.z += v1.z; a1.w += v1.w;
                a2.x += v2.x; a2.y += v2.y; a2.z += v2.z; a2.w += v2.w;
                a3.x += v3.x; a3.y += v3.y; a3.z += v3.z; a3.w += v3.w;
            }
        }
    }
    const size_t o = ((size_t)bh * 64 + i) * 64 + j0;
    *(float4*)(ktvb + o)      = a0;
    *(float4*)(ktvb + o + 4)  = a1;
    *(float4*)(ktvb + o + 8)  = a2;
    *(float4*)(ktvb + o + 12) = a3;
}

__global__ __launch_bounds__(256) void qktv_f32(
    const float* __restrict__ Sq, const float* __restrict__ ktvb,
    float* __restrict__ Y)
{
    const int bh = blockIdx.x;
    const int b = bh >> 4, h = bh & 15;
    __shared__ float kt[64][64];
    const int t = threadIdx.x;
#pragma unroll
    for (int q = 0; q < 16; ++q) {
        const int idx = t + q * 256;
        ((float*)kt)[idx] = ktvb[(size_t)bh * 4096 + idx];
    }
    __syncthreads();
    const int li = t >> 6;
    const int j = t & 63;
    for (int l0 = 0; l0 < LL; l0 += 4) {
        const size_t roff = ((size_t)b * LL + l0 + li) * DIM + h * HDIM;
        const float sqv = Sq[roff + j];
        unsigned long long mask = __ballot(sqv != 0.f);
        float acc = 0.f;
        while (mask) {
            const int i = __ffsll((unsigned long long)mask) - 1;
            mask &= mask - 1;
            acc += kt[i][j];
        }
        const float y = 0.125f * acc;
        Y[roff + j] = (y >= 1.0f) ? 1.0f : 0.0f;
    }
}

// ============================== launch ======================================
extern "C" void kernel_launch(void* const* d_in, const int* in_sizes, int n_in,
                              void* d_out, int out_size, void* d_ws, size_t ws_size,
                              hipStream_t stream)
{
    const float* x        = (const float*)d_in[0];
    const float* q_w      = (const float*)d_in[1];
    const float* q_g      = (const float*)d_in[2];
    const float* q_b      = (const float*)d_in[3];
    const float* k_w      = (const float*)d_in[4];
    const float* k_g      = (const float*)d_in[5];
    const float* k_b      = (const float*)d_in[6];
    const float* v_w      = (const float*)d_in[7];
    const float* v_g      = (const float*)d_in[8];
    const float* v_b      = (const float*)d_in[9];
    const float* proj_w   = (const float*)d_in[10];
    const float* proj_bias= (const float*)d_in[11];
    const float* proj_g   = (const float*)d_in[12];
    const float* proj_beta= (const float*)d_in[13];
    const float* fc1_w    = (const float*)d_in[14];
    const float* fc1_bias = (const float*)d_in[15];
    const float* fc1_g    = (const float*)d_in[16];
    const float* fc1_beta = (const float*)d_in[17];
    const float* fc2_w    = (const float*)d_in[18];
    const float* fc2_bias = (const float*)d_in[19];
    const float* fc2_g    = (const float*)d_in[20];
    const float* fc2_beta = (const float*)d_in[21];

    const dim3 blk(256);
    const size_t NEEDED = 143654912;

    if (ws_size >= NEEDED) {
        char* ws = (char*)d_ws;
        float* U    = (float*)ws;
        float* Up2  = U + (size_t)NROWS * DIM;    // split-K partial 1 (z=1)
        u16*   Xsh  = (u16*)(ws + 67108864);
        u16*   Wbuf = (u16*)(ws + 100663296);
        u16*   Sq   = (u16*)(ws + 125829120);
        u16*   Sk   = (u16*)(ws + 134217728);
        u16*   SvYb = (u16*)((char*)Xsh + 25165824);
        u16*   Xs   = Xsh;          // [4096][3072]
        u16*   X1s  = Xsh;          // [4096][3072] (after Xs dead)
        u16*   Sm   = Xsh;          // [4096][4096] (after X1s dead)
        float* X1   = (float*)d_out;
        // ktv partials (4 MB) alias the Wbuf region (dead during attention)
        float* ktvp = (float*)(ws + 100663296);

        // 6-product exact fp32xfp32 plane pairs: (0,0)(1,1)(2,0)(0,2)(1,0)(0,1)
        const int pa6[6] = {0, 1, 2, 0, 1, 0}, pb6[6] = {0, 1, 0, 2, 0, 1};
        unsigned apack = 0, bpack = 0;
        for (int i = 0; i < 6; ++i) {
            apack |= (unsigned)pa6[i] << (4 * i);
            bpack |= (unsigned)pb6[i] << (4 * i);
        }
        SegList segP;  // spike x fp32, proj (K=1024/plane; Kseg=512, z in {0,1})
        {
            for (int i = 0; i < 6; ++i) { segP.a[i] = 0; segP.b[i] = 0; }
            segP.b[1] = 1024; segP.b[2] = 2048; segP.n = 3;
        }
        SegList segF2; // spike x fp32, fc2 (K=4096/plane; Kseg=2048, z in {0,1})
        {
            for (int i = 0; i < 6; ++i) { segF2.a[i] = 0; segF2.b[i] = 0; }
            segF2.b[1] = 4096; segF2.b[2] = 8192; segF2.n = 3;
        }

        split3_rows<<<dim3(1, NROWS), blk, 0, stream>>>(x, Xs, DIM);

        // merged q|k|v: Wt rows 0..1023 = q, 1024..2047 = k, 2048..3071 = v
        split_wt<<<dim3(16, 16), blk, 0, stream>>>(q_w, Wbuf,               DIM, DIM, 3072);
        split_wt<<<dim3(16, 16), blk, 0, stream>>>(k_w, Wbuf + 1024 * 3072, DIM, DIM, 3072);
        split_wt<<<dim3(16, 16), blk, 0, stream>>>(v_w, Wbuf + 2048 * 3072, DIM, DIM, 3072);
        gemm256<<<dim3(12, 16), dim3(512), 0, stream>>>(
            Xs, 3072, Wbuf, 3072, apack, bpack, 96, nullptr, U, 3072);
        lnlif2<DIM><<<NROWS, blk, 0, stream>>>(U, nullptr, 3072, 0,    q_g, q_b, nullptr, Sq,   nullptr, nullptr);
        lnlif2<DIM><<<NROWS, blk, 0, stream>>>(U, nullptr, 3072, 1024, k_g, k_b, nullptr, Sk,   nullptr, nullptr);
        lnlif2<DIM><<<NROWS, blk, 0, stream>>>(U, nullptr, 3072, 2048, v_g, v_b, nullptr, SvYb, nullptr, nullptr);

        // attention (exact): 4x partial ktv counts, then 0.125*q@ktv, LIF 0.5
        ktv_part<<<dim3(NB * NH, 4), blk, 0, stream>>>(Sk, SvYb, ktvp);
        qktv_bf16<<<dim3(NB * NH, 8), blk, 0, stream>>>(Sq, ktvp, SvYb);

        // proj (split-K x2) + LN + LIF; residual-1 into d_out (X1) + X1s planes
        split_wt<<<dim3(16, 16), blk, 0, stream>>>(proj_w, Wbuf, DIM, DIM, 3072);
        gemm_mfma<64><<<dim3(16, 32, 2), blk, 0, stream>>>(
            SvYb, 1024, Wbuf, 3072, segP, 512, proj_bias, U, DIM);
        lnlif2<DIM><<<NROWS, blk, 0, stream>>>(U, Up2, DIM, 0, proj_g, proj_beta, x, nullptr, X1, X1s);

        // fc1 + LN + LIF (spikes bf16 into Sm, overwrites X1s)
        split_wt<<<dim3(64, 16), blk, 0, stream>>>(fc1_w, Wbuf, DIM, HID, 3072);
        gemm256<<<dim3(16, 16), dim3(512), 0, stream>>>(
            X1s, 3072, Wbuf, 3072, apack, bpack, 96, fc1_bias, U, HID);
        lnlif2<HID><<<NROWS, blk, 0, stream>>>(U, nullptr, HID, 0, fc1_g, fc1_beta, nullptr, Sm, nullptr, nullptr);

        // fc2 (split-K x2) + LN + LIF + residual-2 -> d_out
        split_wt<<<dim3(16, 64), blk, 0, stream>>>(fc2_w, Wbuf, HID, DIM, 12288);
        gemm_mfma<64><<<dim3(16, 32, 2), blk, 0, stream>>>(
            Sm, 4096, Wbuf, 12288, segF2, 2048, fc2_bias, U, DIM);
        lnlif2<DIM><<<NROWS, blk, 0, stream>>>(U, Up2, DIM, 0, fc2_g, fc2_beta, X1, nullptr, (float*)d_out, nullptr);
        return;
    }

    // ---- fallback: round-2 fp32 path (verified; needs ~85 MB) ----
    float* U    = (float*)d_ws;
    float* Sq   = U + (size_t)1 * NROWS * DIM;
    float* Sk   = U + (size_t)2 * NROWS * DIM;
    float* Sv   = U + (size_t)3 * NROWS * DIM;
    float* Yb   = Sv;
    float* ktvb = U + (size_t)NROWS * HID;
    float* Y2   = ktvb + (size_t)NB * NH * HDIM * HDIM;
    float* X1   = (float*)d_out;
    float* outf = (float*)d_out;

    const dim3 gemm_d(DIM / BN, NROWS / BM);
    const dim3 gemm_h(HID / BN, NROWS / BM);

    gemm_f32<<<gemm_d, blk, 0, stream>>>(x, q_w, nullptr, U, NROWS, DIM, DIM);
    lnlif_old<DIM><<<NROWS, blk, 0, stream>>>(U, q_g, q_b, 2.0f, nullptr, Sq);
    gemm_f32<<<gemm_d, blk, 0, stream>>>(x, k_w, nullptr, U, NROWS, DIM, DIM);
    lnlif_old<DIM><<<NROWS, blk, 0, stream>>>(U, k_g, k_b, 2.0f, nullptr, Sk);
    gemm_f32<<<gemm_d, blk, 0, stream>>>(x, v_w, nullptr, U, NROWS, DIM, DIM);
    lnlif_old<DIM><<<NROWS, blk, 0, stream>>>(U, v_g, v_b, 2.0f, nullptr, Sv);

    ktv_f32<<<NB * NH, blk, 0, stream>>>(Sk, Sv, ktvb);
    qktv_f32<<<NB * NH, blk, 0, stream>>>(Sq, ktvb, Yb);

    gemm_f32<<<gemm_d, blk, 0, stream>>>(Yb, proj_w, proj_bias, U, NROWS, DIM, DIM);
    lnlif_old<DIM><<<NROWS, blk, 0, stream>>>(U, proj_g, proj_beta, 2.0f, x, X1);

    gemm_f32<<<gemm_h, blk, 0, stream>>>(X1, fc1_w, fc1_bias, U, NROWS, DIM, HID);
    lnlif_old<HID><<<NROWS, blk, 0, stream>>>(U, fc1_g, fc1_beta, 2.0f, nullptr, U);

    gemm_f32<<<gemm_d, blk, 0, stream>>>(U, fc2_w, fc2_bias, Y2, NROWS, HID, DIM);
    lnlif_old<DIM><<<NROWS, blk, 0, stream>>>(Y2, fc2_g, fc2_beta, 2.0f, X1, outf);
}

// Round 17
// 588.434 us; speedup vs baseline: 1.0304x; 1.0304x over previous
//
#include <hip/hip_runtime.h>
#include <hip/hip_bf16.h>

// Spikformer block on MI355X.
// Fast path: exact bf16-split MFMA GEMMs (fp32 = 3 bf16 planes; 6 products for
// fp32 x fp32, 3 products for binary-spike x fp32) + fused LN+LIF + exact
// sparse spike-attention (0.125 * q @ (k^T @ v), integer counts).
// R17 = R13 revert (verified 588.8 us): R16's deep-prefetch regressed
// (bunched stage traffic + phase imbalance). gemm256: gray-code persistent
// operand regs, counted vmcnt(4) x3 per tile, compiler-scheduled lgkmcnt.
// proj/fc2 split-K x2 (R12), split-attention + vectorized lnlif (R8).
// Fallback path (ws_size too small): round-2 fp32 VALU pipeline (verified).

#define NB 4
#define LL 1024
#define DIM 1024
#define NH 16
#define HDIM 64
#define HID 4096
#define NROWS (NB * LL)

typedef unsigned short u16;
typedef __attribute__((ext_vector_type(8))) short short8v;   // 8 bf16 (4 VGPRs)
typedef __attribute__((ext_vector_type(4))) float f32x4;     // MFMA acc

// ---------------- bf16 split helpers (RNE; split is exact by construction) ---
__device__ __forceinline__ u16 f2bf(float f) {
    unsigned u = __builtin_bit_cast(unsigned, f);
    return (u16)((u + 0x7fffu + ((u >> 16) & 1u)) >> 16);
}
__device__ __forceinline__ float bf2f(u16 h) {
    unsigned u = ((unsigned)h) << 16;
    return __builtin_bit_cast(float, u);
}
__device__ __forceinline__ void split3v(float v, u16& a, u16& b, u16& c) {
    a = f2bf(v);
    float r = v - bf2f(a);
    b = f2bf(r);
    float r2 = r - bf2f(b);
    c = f2bf(r2);
}

// ---------------- split x (f32 [M][K]) -> planes bf16 [M][3K] ----------------
__global__ __launch_bounds__(256) void split3_rows(
    const float* __restrict__ X, u16* __restrict__ Xs, int K)
{
    const int row = blockIdx.y;
    const int c4 = (blockIdx.x * 256 + threadIdx.x) * 4;
    if (c4 >= K) return;
    float4 v = *(const float4*)(X + (size_t)row * K + c4);
    float vv[4] = {v.x, v.y, v.z, v.w};
    u16 h0[4], h1[4], h2[4];
#pragma unroll
    for (int j = 0; j < 4; ++j) split3v(vv[j], h0[j], h1[j], h2[j]);
    u16* base = Xs + (size_t)row * 3 * K + c4;
    *(uint2*)(base + 0 * K) = *(uint2*)h0;
    *(uint2*)(base + 1 * K) = *(uint2*)h1;
    *(uint2*)(base + 2 * K) = *(uint2*)h2;
}

// ------------- split + transpose W (f32 [K][N]) -> Wt bf16 [N][3K] -----------
__global__ __launch_bounds__(256) void split_wt(
    const float* __restrict__ W, u16* __restrict__ Wt, int K, int N, int ldwt)
{
    __shared__ float tile[64][65];   // [n][k], padded
    const int k0 = blockIdx.y * 64, n0 = blockIdx.x * 64;
    const int t = threadIdx.x;
    const int rr = t >> 4;            // 0..15 (k within chunk)
    const int cc = (t & 15) * 4;      // 0..60 (n)
#pragma unroll
    for (int it = 0; it < 4; ++it) {
        const int k = rr + it * 16;
        float4 v = *(const float4*)(W + (size_t)(k0 + k) * N + n0 + cc);
        tile[cc + 0][k] = v.x; tile[cc + 1][k] = v.y;
        tile[cc + 2][k] = v.z; tile[cc + 3][k] = v.w;
    }
    __syncthreads();
    const int n = t >> 2, kc = (t & 3) * 16;
    u16 h0[16], h1[16], h2[16];
#pragma unroll
    for (int j = 0; j < 16; ++j)
        split3v(tile[n][kc + j], h0[j], h1[j], h2[j]);
    u16* base = Wt + (size_t)(n0 + n) * ldwt + k0 + kc;
    *(uint4*)(base + 0 * K)     = ((uint4*)h0)[0];
    *(uint4*)(base + 0 * K + 8) = ((uint4*)h0)[1];
    *(uint4*)(base + 1 * K)     = ((uint4*)h1)[0];
    *(uint4*)(base + 1 * K + 8) = ((uint4*)h1)[1];
    *(uint4*)(base + 2 * K)     = ((uint4*)h2)[0];
    *(uint4*)(base + 2 * K + 8) = ((uint4*)h2)[1];
}

#define AS1G const __attribute__((address_space(1))) void*
#define AS3L __attribute__((address_space(3))) void*

// ============ 256^2 8-wave double-buffered GEMM, counted vmcnt ==============
// Kseg=1024 per seg, BK=64, nt K-tiles total; seg plane ids packed 4-bit in
// apack/bpack (column offset = plane*1024 + (tile&15)*64).
// A bf16 [M][lda] row-major; Bt bf16 [N][ldb] (k contiguous per output col).
// LDS 128KB: 2 buf x (A 32KB + B 32KB).  A LDS row = tile row (identity).
// B LDS row rho <-> global col: c(rho) = ((rho>>5)&3)*64 + (rho>>7)*32 + (rho&31).
// 16B-slot swizzle: LDS slot s of row r holds logical slot s^(r&7).
// Gray-code quadrant order (0,0)->(1,0)->(1,1)->(0,1): persistent operand regs,
// phases load only the changed operand: 12+8+4+0 ds_read_b128 per K-tile.
// No manual lgkmcnt drain — ds_read->MFMA deps are compiler-visible, so hipcc
// emits fine-grained lgkmcnt; vmcnt/barrier discipline explicit.
__global__ __launch_bounds__(512, 2) void gemm256(
    const u16* __restrict__ A, int lda,
    const u16* __restrict__ Bt, int ldb,
    unsigned apack, unsigned bpack, int nt,
    const float* __restrict__ bias,
    float* __restrict__ Out, int ldo)
{
    __shared__ u16 As2[2][16384];
    __shared__ u16 Bs2[2][16384];
    const int t = threadIdx.x;
    const int wid = t >> 6, lane = t & 63;
    const int wm = wid >> 2, wn = wid & 3;          // 2 x 4 wave grid
    // XCD-aware tile swizzle (bijective: nwg is a multiple of 8)
    int bid = blockIdx.y * gridDim.x + blockIdx.x;
    const int nwg = gridDim.x * gridDim.y;
    bid = (bid & 7) * (nwg >> 3) + (bid >> 3);
    const int row0 = (bid / gridDim.x) * 256, col0 = (bid % gridDim.x) * 256;
    const int lrow = lane & 15, lk = lane >> 4;
    const int sr0 = t >> 3;                         // 0..63 row in stage region
    const int scol = ((t & 7) ^ (sr0 & 7)) * 8;     // pre-swizzled source slot

    f32x4 acc[8][4];
#pragma unroll
    for (int i = 0; i < 8; ++i)
#pragma unroll
        for (int j = 0; j < 4; ++j) acc[i][j] = f32x4{0.f, 0.f, 0.f, 0.f};
    short8v afA[4][2], afB[4][2], bf[2][2];         // persistent operand regs

#define STA(bs, Rb, c0)                                                        \
    __builtin_amdgcn_global_load_lds(                                          \
        (AS1G)(A + (size_t)(row0 + (Rb) + sr0) * lda + (c0) + scol),           \
        (AS3L)(&As2[bs][(Rb) * 64 + t * 8]), 16, 0, 0);
#define STB(bs, Rb, c0)                                                        \
    {                                                                          \
        const int _rho = (Rb) + sr0;                                           \
        const int _bc = ((_rho >> 5) & 3) * 64 + ((_rho >> 7) << 5) + (_rho & 31); \
        __builtin_amdgcn_global_load_lds(                                      \
            (AS1G)(Bt + (size_t)(col0 + _bc) * ldb + (c0) + scol),             \
            (AS3L)(&Bs2[bs][(Rb) * 64 + t * 8]), 16, 0, 0);                    \
    }
#define STPAIR0(bs, cA, cB) STA(bs, 0, cA)   STA(bs, 128, cA)
#define STPAIR1(bs, cA, cB) STB(bs, 0, cB)   STB(bs, 64, cB)
#define STPAIR2(bs, cA, cB) STA(bs, 64, cA)  STA(bs, 192, cA)
#define STPAIR3(bs, cA, cB) STB(bs, 128, cB) STB(bs, 192, cB)

#define VMW(n) asm volatile("s_waitcnt vmcnt(" #n ")" ::: "memory");
#define BAR  __builtin_amdgcn_s_barrier();
#define BARP                                                                   \
    __builtin_amdgcn_s_barrier();                                              \
    __builtin_amdgcn_sched_barrier(0);

#define LDA(dst, MQ, P)                                                        \
    _Pragma("unroll")                                                          \
    for (int mf = 0; mf < 4; ++mf) {                                           \
        const int r = wm * 128 + (MQ) * 64 + mf * 16 + lrow;                   \
        _Pragma("unroll")                                                      \
        for (int ks = 0; ks < 2; ++ks) {                                       \
            const int slot = (lk + ks * 4) ^ (r & 7);                          \
            dst[mf][ks] = *(const short8v*)&As2[P][r * 64 + slot * 8];         \
        }                                                                      \
    }
#define LDB(NQ, P)                                                             \
    _Pragma("unroll")                                                          \
    for (int nf = 0; nf < 2; ++nf) {                                           \
        const int rho = (NQ) * 128 + (wn >> 1) * 64 + (wn & 1) * 32            \
                        + nf * 16 + lrow;                                      \
        _Pragma("unroll")                                                      \
        for (int ks = 0; ks < 2; ++ks) {                                       \
            const int slot = (lk + ks * 4) ^ (rho & 7);                        \
            bf[nf][ks] = *(const short8v*)&Bs2[P][rho * 64 + slot * 8];        \
        }                                                                      \
    }
#define MM(asrc, MQ, NQ)                                                       \
    __builtin_amdgcn_s_setprio(1);                                             \
    _Pragma("unroll")                                                          \
    for (int mf = 0; mf < 4; ++mf)                                             \
        _Pragma("unroll")                                                      \
        for (int nf = 0; nf < 2; ++nf)                                         \
            _Pragma("unroll")                                                  \
            for (int ks = 0; ks < 2; ++ks)                                     \
                acc[(MQ) * 4 + mf][(NQ) * 2 + nf] =                            \
                    __builtin_amdgcn_mfma_f32_16x16x32_bf16(                   \
                        asrc[mf][ks], bf[nf][ks],                              \
                        acc[(MQ) * 4 + mf][(NQ) * 2 + nf], 0, 0, 0);           \
    __builtin_amdgcn_s_setprio(0);

    // prologue: stage K-tile 0 (8 loads) into buf 0.
    {
        const int cA = (apack & 15) * 1024;
        const int cB = (bpack & 15) * 1024;
        STPAIR0(0, cA, cB) STPAIR1(0, cA, cB)
        STPAIR2(0, cA, cB) STPAIR3(0, cA, cB)
    }

    for (int kt = 0; kt < nt - 1; ++kt) {
        const int p = kt & 1, np = p ^ 1;
        const int nkt = kt + 1;
        const int nns = nkt >> 4, nk0 = (nkt & 15) * 64;
        const int nA = (int)((apack >> (nns * 4)) & 15) * 1024 + nk0;
        const int nB = (int)((bpack >> (nns * 4)) & 15) * 1024 + nk0;
        VMW(4) BARP   // S0..S3 done
        LDA(afA, 0, p) LDB(0, p) STPAIR0(np, nA, nB) MM(afA, 0, 0)
        VMW(4) BAR    // S4,S5 done
        LDA(afB, 1, p) STPAIR1(np, nA, nB) MM(afB, 1, 0)
        VMW(4) BAR    // S6,S7 done
        LDB(1, p) STPAIR2(np, nA, nB) MM(afB, 1, 1)
        BAR           // nothing new needed; operands already in regs
        STPAIR3(np, nA, nB) MM(afA, 0, 1)
    }
    // epilogue tile (no stages): waits drain 4 -> 2 -> 0.
    {
        const int p = (nt - 1) & 1;
        VMW(4) BARP LDA(afA, 0, p) LDB(0, p) MM(afA, 0, 0)
        VMW(2) BAR  LDA(afB, 1, p) MM(afB, 1, 0)
        VMW(0) BAR  LDB(1, p) MM(afB, 1, 1)
        BAR         MM(afA, 0, 1)
    }
#undef STPAIR0
#undef STPAIR1
#undef STPAIR2
#undef STPAIR3
#undef LDA
#undef LDB
#undef MM

    // epilogue: C/D layout col=lane&15, row=(lane>>4)*4+reg  [m89-verified]
#pragma unroll
    for (int ni = 0; ni < 4; ++ni) {
        const int col = col0 + wn * 64 + ni * 16 + lrow;
        const float bv = bias ? bias[col] : 0.f;
#pragma unroll
        for (int mi = 0; mi < 8; ++mi) {
            const int rbase = row0 + wm * 128 + mi * 16 + lk * 4;
#pragma unroll
            for (int r = 0; r < 4; ++r)
                Out[(size_t)(rbase + r) * ldo + col] = acc[mi][ni][r] + bv;
        }
    }
#undef STA
#undef STB
#undef VMW
#undef BAR
#undef BARP
}

// ---------------- 128^2 MFMA GEMM (verified 2-barrier) with split-K ----------
// blockIdx.z selects a K-half: seg offsets shifted by z*Kseg, output written to
// partial buffer z (Out + z * M * ldo). Bias added only in z == 0.
struct SegList { int a[6]; int b[6]; int n; };

template <int BN_>
__global__ __launch_bounds__(256) void gemm_mfma(
    const u16* __restrict__ A, int lda,
    const u16* __restrict__ Bt, int ldb,
    SegList segs, int Kseg,
    const float* __restrict__ bias,
    float* __restrict__ Out, int ldo)
{
    constexpr int NF = BN_ / 32;              // B-frags per wave (2 or 4)
    __shared__ u16 As[128 * 64];              // 16 KB
    __shared__ u16 Bs[BN_ * 64];              // 8/16 KB
    const int t = threadIdx.x;
    const int wid = t >> 6, lane = t & 63;
    const int wr = wid >> 1, wc = wid & 1;
    const int z = blockIdx.z;
    const int koff = z * Kseg;
    Out += (size_t)z * (size_t)gridDim.y * 128 * ldo;
    // XCD-aware tile swizzle (bijective: nwg is a multiple of 8)
    int bid = blockIdx.y * gridDim.x + blockIdx.x;
    const int nwg = gridDim.x * gridDim.y;
    bid = (bid & 7) * (nwg >> 3) + (bid >> 3);
    const int row0 = (bid / gridDim.x) * 128, col0 = (bid % gridDim.x) * BN_;
    const int lrow = lane & 15;
    const int s_subrow = lane >> 3;                       // 0..7
    const int s_slot   = (lane & 7) ^ (lane >> 3);        // pre-swizzled slot
    const int s_coff   = s_slot * 8;

    f32x4 acc[4][NF];
#pragma unroll
    for (int i = 0; i < 4; ++i)
#pragma unroll
        for (int j = 0; j < NF; ++j) acc[i][j] = f32x4{0.f, 0.f, 0.f, 0.f};

    for (int s = 0; s < segs.n; ++s) {
        const u16* pa = A + segs.a[s] + koff;
        const u16* pb = Bt + segs.b[s] + koff;
        for (int k0 = 0; k0 < Kseg; k0 += 64) {
            asm volatile("s_waitcnt lgkmcnt(0)" ::: "memory");
            __syncthreads();
#pragma unroll
            for (int c = 0; c < 4; ++c) {          // A tile: 16 chunks, 4/wave
                const int chunk = wid * 4 + c;
                const int rg = row0 + chunk * 8 + s_subrow;
                __builtin_amdgcn_global_load_lds(
                    (AS1G)(pa + (size_t)rg * lda + k0 + s_coff),
                    (AS3L)(&As[chunk * 512 + lane * 8]), 16, 0, 0);
            }
#pragma unroll
            for (int c = 0; c < NF; ++c) {         // B tile
                const int chunk = wid * NF + c;
                const int rg = col0 + chunk * 8 + s_subrow;
                __builtin_amdgcn_global_load_lds(
                    (AS1G)(pb + (size_t)rg * ldb + k0 + s_coff),
                    (AS3L)(&Bs[chunk * 512 + lane * 8]), 16, 0, 0);
            }
            asm volatile("s_waitcnt vmcnt(0)" ::: "memory");
            __syncthreads();
#pragma unroll
            for (int ksub = 0; ksub < 2; ++ksub) {
                short8v af[4], bfr[NF];
#pragma unroll
                for (int f = 0; f < 4; ++f) {
                    const int ra = wr * 64 + f * 16 + lrow;
                    const int slot = ((lane >> 4) + ksub * 4) ^ (lrow & 7);
                    af[f] = *(const short8v*)&As[ra * 64 + slot * 8];
                }
#pragma unroll
                for (int f = 0; f < NF; ++f) {
                    const int rb = wc * (BN_ / 2) + f * 16 + lrow;
                    const int slot = ((lane >> 4) + ksub * 4) ^ (lrow & 7);
                    bfr[f] = *(const short8v*)&Bs[rb * 64 + slot * 8];
                }
#pragma unroll
                for (int i = 0; i < 4; ++i)
#pragma unroll
                    for (int j = 0; j < NF; ++j)
                        acc[i][j] = __builtin_amdgcn_mfma_f32_16x16x32_bf16(
                            af[i], bfr[j], acc[i][j], 0, 0, 0);
            }
        }
    }
#pragma unroll
    for (int j = 0; j < NF; ++j) {
        const int col = col0 + wc * (BN_ / 2) + j * 16 + lrow;
        const float bv = (bias && z == 0) ? bias[col] : 0.f;
#pragma unroll
        for (int i = 0; i < 4; ++i) {
            const int rbase = row0 + wr * 64 + i * 16 + (lane >> 4) * 4;
#pragma unroll
            for (int r = 0; r < 4; ++r)
                Out[(size_t)(rbase + r) * ldo + col] = acc[i][j][r] + bv;
        }
    }
}

// ---------------- fused LN + LIF, multi-output (float4-vectorized) ----------
// Optional U2: second partial buffer summed on load (split-K reduce).
template <int DN>
__global__ __launch_bounds__(256) void lnlif2(
    const float* __restrict__ U, const float* __restrict__ U2, int ld, int coloff,
    const float* __restrict__ g, const float* __restrict__ beta,
    const float* __restrict__ resid,
    u16* __restrict__ spike_bf16,
    float* __restrict__ out_f32,
    u16* __restrict__ split3_out)
{
    constexpr int PT = DN / 1024;    // float4s per thread (1 for 1024, 4 for 4096)
    const int r = blockIdx.x, t = threadIdx.x;
    const float4* u4 = (const float4*)(U + (size_t)r * ld + coloff);
    const float4* u24 = U2 ? (const float4*)(U2 + (size_t)r * ld + coloff) : nullptr;
    float4 vals[PT];
    float lsum = 0.f;
#pragma unroll
    for (int i = 0; i < PT; ++i) {
        vals[i] = u4[t + i * 256];
        if (u24) {
            float4 w = u24[t + i * 256];
            vals[i].x += w.x; vals[i].y += w.y;
            vals[i].z += w.z; vals[i].w += w.w;
        }
        lsum += (vals[i].x + vals[i].y) + (vals[i].z + vals[i].w);
    }
    __shared__ float red[4];
    __shared__ float bcast;
    for (int o = 32; o > 0; o >>= 1) lsum += __shfl_down(lsum, o);
    if ((t & 63) == 0) red[t >> 6] = lsum;
    __syncthreads();
    if (t == 0) bcast = (red[0] + red[1] + red[2] + red[3]) * (1.f / DN);
    __syncthreads();
    const float m = bcast;
    float lss = 0.f;
#pragma unroll
    for (int i = 0; i < PT; ++i) {
        float dx = vals[i].x - m, dy = vals[i].y - m;
        float dz = vals[i].z - m, dw = vals[i].w - m;
        lss += (dx * dx + dy * dy) + (dz * dz + dw * dw);
    }
    for (int o = 32; o > 0; o >>= 1) lss += __shfl_down(lss, o);
    if ((t & 63) == 0) red[t >> 6] = lss;
    __syncthreads();
    if (t == 0) bcast = (red[0] + red[1] + red[2] + red[3]) * (1.f / DN);
    __syncthreads();
    const float rs = 1.f / sqrtf(bcast + 1e-5f);
#pragma unroll
    for (int i = 0; i < PT; ++i) {
        const int c = (t + i * 256) * 4;
        const size_t idx = (size_t)r * DN + c;
        const float4 gg = *(const float4*)(g + c);
        const float4 bb = *(const float4*)(beta + c);
        float sv[4];
        sv[0] = ((vals[i].x - m) * rs * gg.x + bb.x >= 2.0f) ? 1.f : 0.f;
        sv[1] = ((vals[i].y - m) * rs * gg.y + bb.y >= 2.0f) ? 1.f : 0.f;
        sv[2] = ((vals[i].z - m) * rs * gg.z + bb.z >= 2.0f) ? 1.f : 0.f;
        sv[3] = ((vals[i].w - m) * rs * gg.w + bb.w >= 2.0f) ? 1.f : 0.f;
        if (spike_bf16) {
            u16 sp[4];
#pragma unroll
            for (int j = 0; j < 4; ++j) sp[j] = sv[j] != 0.f ? (u16)0x3F80 : (u16)0;
            *(uint2*)(spike_bf16 + idx) = *(uint2*)sp;
        }
        if (out_f32 || split3_out) {
            float4 rv = resid ? *(const float4*)(resid + idx)
                              : float4{0.f, 0.f, 0.f, 0.f};
            float vv[4] = {rv.x + sv[0], rv.y + sv[1], rv.z + sv[2], rv.w + sv[3]};
            if (out_f32) {
                float4 ov = {vv[0], vv[1], vv[2], vv[3]};
                *(float4*)(out_f32 + idx) = ov;
            }
            if (split3_out) {
                u16 h0[4], h1[4], h2[4];
#pragma unroll
                for (int j = 0; j < 4; ++j) split3v(vv[j], h0[j], h1[j], h2[j]);
                u16* base = split3_out + (size_t)r * 3 * DN + c;
                *(uint2*)(base + 0 * DN) = *(uint2*)h0;
                *(uint2*)(base + 1 * DN) = *(uint2*)h1;
                *(uint2*)(base + 2 * DN) = *(uint2*)h2;
            }
        }
    }
}

// ------- attention: ktv partials (split L into 4 chunks; exact counts) -------
__global__ __launch_bounds__(256) void ktv_part(
    const u16* __restrict__ Sk, const u16* __restrict__ Sv,
    float* __restrict__ ktvp)
{
    const int bh = blockIdx.x, ck = blockIdx.y;    // ck: L-chunk 0..3
    const int b = bh >> 4, h = bh & 15;
    __shared__ float kch[64][64];
    __shared__ float vch[64][64];
    const int t = threadIdx.x;
    const int i = t >> 2;
    const int j0 = (t & 3) << 4;
    float4 a0 = {0,0,0,0}, a1 = {0,0,0,0}, a2 = {0,0,0,0}, a3 = {0,0,0,0};
    for (int l0 = ck * 256; l0 < ck * 256 + 256; l0 += 64) {
        __syncthreads();
#pragma unroll
        for (int q = 0; q < 2; ++q) {
            const int chunk = t + q * 256;
            const int li = chunk >> 3, c8 = (chunk & 7) << 3;
            const size_t off = ((size_t)b * LL + l0 + li) * DIM + h * HDIM + c8;
            union { uint4 v; u16 s[8]; } uk, uv;
            uk.v = *(const uint4*)(Sk + off);
            uv.v = *(const uint4*)(Sv + off);
#pragma unroll
            for (int j = 0; j < 8; ++j) {
                kch[li][c8 + j] = uk.s[j] ? 1.f : 0.f;
                vch[li][c8 + j] = uv.s[j] ? 1.f : 0.f;
            }
        }
        __syncthreads();
        for (int l = 0; l < 64; ++l) {
            if (kch[l][i] != 0.f) {
                const float4 v0 = *(float4*)&vch[l][j0];
                const float4 v1 = *(float4*)&vch[l][j0 + 4];
                const float4 v2 = *(float4*)&vch[l][j0 + 8];
                const float4 v3 = *(float4*)&vch[l][j0 + 12];
                a0.x += v0.x; a0.y += v0.y; a0.z += v0.z; a0.w += v0.w;
                a1.x += v1.x; a1.y += v1.y; a1.z += v1.z; a1.w += v1.w;
                a2.x += v2.x; a2.y += v2.y; a2.z += v2.z; a2.w += v2.w;
                a3.x += v3.x; a3.y += v3.y; a3.z += v3.z; a3.w += v3.w;
            }
        }
    }
    const size_t o = (((size_t)ck * 64 + bh) * 64 + i) * 64 + j0;
    *(float4*)(ktvp + o)      = a0;
    *(float4*)(ktvp + o + 4)  = a1;
    *(float4*)(ktvp + o + 8)  = a2;
    *(float4*)(ktvp + o + 12) = a3;
}

// --- attention: q@(ktv), LIF(v_th=0.5); sums 4 partials (fixed order, exact) --
__global__ __launch_bounds__(256) void qktv_bf16(
    const u16* __restrict__ Sq, const float* __restrict__ ktvp,
    u16* __restrict__ Y)
{
    const int bh = blockIdx.x, ck = blockIdx.y;    // ck: row-chunk 0..7
    const int b = bh >> 4, h = bh & 15;
    __shared__ float kt[64][64];
    const int t = threadIdx.x;
#pragma unroll
    for (int q = 0; q < 16; ++q) {
        const int idx = t + q * 256;
        ((float*)kt)[idx] = (ktvp[((size_t)0 * 64 + bh) * 4096 + idx]
                           + ktvp[((size_t)1 * 64 + bh) * 4096 + idx])
                          + (ktvp[((size_t)2 * 64 + bh) * 4096 + idx]
                           + ktvp[((size_t)3 * 64 + bh) * 4096 + idx]);
    }
    __syncthreads();
    const int li = t >> 6;
    const int j = t & 63;
    for (int l0 = ck * 128; l0 < ck * 128 + 128; l0 += 4) {
        const size_t roff = ((size_t)b * LL + l0 + li) * DIM + h * HDIM;
        const u16 sqv = Sq[roff + j];
        unsigned long long mask = __ballot(sqv != 0);
        float acc = 0.f;
        while (mask) {
            const int i = __ffsll((unsigned long long)mask) - 1;
            mask &= mask - 1;
            acc += kt[i][j];
        }
        const float y = 0.125f * acc;
        Y[roff + j] = (y >= 1.0f) ? (u16)0x3F80 : (u16)0;
    }
}

// ======================= FALLBACK (round-2 fp32 path) ========================
#define BM 128
#define BN 128
#define BK 16

__global__ __launch_bounds__(256) void gemm_f32(
    const float* __restrict__ A, const float* __restrict__ W,
    const float* __restrict__ bias, float* __restrict__ U,
    int M, int K, int N)
{
    __shared__ float As[BK][BM];
    __shared__ float Bs[BK][BN];
    const int t = threadIdx.x;
    const int tx = t & 15, ty = t >> 4;
    const int row0 = blockIdx.y * BM, col0 = blockIdx.x * BN;
    const int ar = t >> 2;
    const int ac = (t & 3) << 2;
    const int br = t >> 5;
    const int bc = (t & 31) << 2;
    float acc[8][8];
#pragma unroll
    for (int i = 0; i < 8; ++i)
#pragma unroll
        for (int j = 0; j < 8; ++j) acc[i][j] = 0.f;
    for (int k0 = 0; k0 < K; k0 += BK) {
        float4 va0 = *(const float4*)(A + (size_t)(row0 + ar) * K + k0 + ac);
        float4 va1 = *(const float4*)(A + (size_t)(row0 + ar + 64) * K + k0 + ac);
        float4 vb0 = *(const float4*)(W + (size_t)(k0 + br) * N + col0 + bc);
        float4 vb1 = *(const float4*)(W + (size_t)(k0 + br + 8) * N + col0 + bc);
        __syncthreads();
        As[ac + 0][ar] = va0.x; As[ac + 1][ar] = va0.y;
        As[ac + 2][ar] = va0.z; As[ac + 3][ar] = va0.w;
        As[ac + 0][ar + 64] = va1.x; As[ac + 1][ar + 64] = va1.y;
        As[ac + 2][ar + 64] = va1.z; As[ac + 3][ar + 64] = va1.w;
        *(float4*)&Bs[br][bc] = vb0;
        *(float4*)&Bs[br + 8][bc] = vb1;
        __syncthreads();
#pragma unroll
        for (int kk = 0; kk < BK; ++kk) {
            float4 fa0 = *(float4*)&As[kk][ty * 8];
            float4 fa1 = *(float4*)&As[kk][ty * 8 + 4];
            float4 fb0 = *(float4*)&Bs[kk][tx * 8];
            float4 fb1 = *(float4*)&Bs[kk][tx * 8 + 4];
            float av[8] = {fa0.x, fa0.y, fa0.z, fa0.w, fa1.x, fa1.y, fa1.z, fa1.w};
            float bv[8] = {fb0.x, fb0.y, fb0.z, fb0.w, fb1.x, fb1.y, fb1.z, fb1.w};
#pragma unroll
            for (int i = 0; i < 8; ++i)
#pragma unroll
                for (int j = 0; j < 8; ++j)
                    acc[i][j] += av[i] * bv[j];
        }
    }
    float bvals[8];
#pragma unroll
    for (int j = 0; j < 8; ++j)
        bvals[j] = bias ? bias[col0 + tx * 8 + j] : 0.f;
#pragma unroll
    for (int i = 0; i < 8; ++i) {
        const int row = row0 + ty * 8 + i;
        float* dst = U + (size_t)row * N + col0 + tx * 8;
        float4 o0, o1;
        o0.x = acc[i][0] + bvals[0]; o0.y = acc[i][1] + bvals[1];
        o0.z = acc[i][2] + bvals[2]; o0.w = acc[i][3] + bvals[3];
        o1.x = acc[i][4] + bvals[4]; o1.y = acc[i][5] + bvals[5];
        o1.z = acc[i][6] + bvals[6]; o1.w = acc[i][7] + bvals[7];
        *(float4*)dst = o0;
        *(float4*)(dst + 4) = o1;
    }
}

template <int DN>
__global__ __launch_bounds__(256) void lnlif_old(
    const float* __restrict__ U, const float* __restrict__ g,
    const float* __restrict__ beta, float thr,
    const float* __restrict__ resid, float* __restrict__ out)
{
    constexpr int PT = DN / 256;
    const int r = blockIdx.x, t = threadIdx.x;
    const float* u = U + (size_t)r * DN;
    float vals[PT];
    float lsum = 0.f;
#pragma unroll
    for (int i = 0; i < PT; ++i) { vals[i] = u[t + i * 256]; lsum += vals[i]; }
    __shared__ float red[4];
    __shared__ float bc0;
    for (int o = 32; o > 0; o >>= 1) lsum += __shfl_down(lsum, o);
    if ((t & 63) == 0) red[t >> 6] = lsum;
    __syncthreads();
    if (t == 0) bc0 = (red[0] + red[1] + red[2] + red[3]) * (1.f / DN);
    __syncthreads();
    const float m = bc0;
    float lss = 0.f;
#pragma unroll
    for (int i = 0; i < PT; ++i) { float d = vals[i] - m; lss += d * d; }
    for (int o = 32; o > 0; o >>= 1) lss += __shfl_down(lss, o);
    if ((t & 63) == 0) red[t >> 6] = lss;
    __syncthreads();
    if (t == 0) bc0 = (red[0] + red[1] + red[2] + red[3]) * (1.f / DN);
    __syncthreads();
    const float rs = 1.0f / sqrtf(bc0 + 1e-5f);
#pragma unroll
    for (int i = 0; i < PT; ++i) {
        const int c = t + i * 256;
        const float nrm = (vals[i] - m) * rs * g[c] + beta[c];
        const float s = (nrm >= thr) ? 1.0f : 0.0f;
        out[(size_t)r * DN + c] = resid ? (resid[(size_t)r * DN + c] + s) : s;
    }
}

__global__ __launch_bounds__(256) void ktv_f32(
    const float* __restrict__ Sk, const float* __restrict__ Sv,
    float* __restrict__ ktvb)
{
    const int bh = blockIdx.x;
    const int b = bh >> 4, h = bh & 15;
    __shared__ float kch[64][64];
    __shared__ float vch[64][64];
    const int t = threadIdx.x;
    const int i = t >> 2;
    const int j0 = (t & 3) << 4;
    float4 a0 = {0,0,0,0}, a1 = {0,0,0,0}, a2 = {0,0,0,0}, a3 = {0,0,0,0};
    for (int l0 = 0; l0 < LL; l0 += 64) {
        __syncthreads();
#pragma unroll
        for (int q = 0; q < 4; ++q) {
            const int idx = t + q * 256;
            const int li = idx >> 4, c4 = (idx & 15) << 2;
            const size_t off = ((size_t)b * LL + l0 + li) * DIM + h * HDIM + c4;
            *(float4*)&kch[li][c4] = *(const float4*)(Sk + off);
            *(float4*)&vch[li][c4] = *(const float4*)(Sv + off);
        }
        __syncthreads();
        for (int l = 0; l < 64; ++l) {
            if (kch[l][i] != 0.f) {
                const float4 v0 = *(float4*)&vch[l][j0];
                const float4 v1 = *(float4*)&vch[l][j0 + 4];
                const float4 v2 = *(float4*)&vch[l][j0 + 8];
                const float4 v3 = *(float4*)&vch[l][j0 + 12];
                a0.x += v0.x; a0.y += v0.y; a0.z += v0.z; a0.w += v0.w;
                a1.x += v1.x; a1.y += v1.y; a1.z += v1.z; a1.w += v1.w;
                a2.x += v2.x; a2.y += v2.y; a2.z += v2.z; a2.w += v2.w;
                a3.x += v3.x; a3.y += v3.y; a3.z += v3.z; a3.w += v3.w;
            }
        }
    }
    const size_t o = ((size_t)bh * 64 + i) * 64 + j0;
    *(float4*)(ktvb + o)      = a0;
    *(float4*)(ktvb + o + 4)  = a1;
    *(float4*)(ktvb + o + 8)  = a2;
    *(float4*)(ktvb + o + 12) = a3;
}

__global__ __launch_bounds__(256) void qktv_f32(
    const float* __restrict__ Sq, const float* __restrict__ ktvb,
    float* __restrict__ Y)
{
    const int bh = blockIdx.x;
    const int b = bh >> 4, h = bh & 15;
    __shared__ float kt[64][64];
    const int t = threadIdx.x;
#pragma unroll
    for (int q = 0; q < 16; ++q) {
        const int idx = t + q * 256;
        ((float*)kt)[idx] = ktvb[(size_t)bh * 4096 + idx];
    }
    __syncthreads();
    const int li = t >> 6;
    const int j = t & 63;
    for (int l0 = 0; l0 < LL; l0 += 4) {
        const size_t roff = ((size_t)b * LL + l0 + li) * DIM + h * HDIM;
        const float sqv = Sq[roff + j];
        unsigned long long mask = __ballot(sqv != 0.f);
        float acc = 0.f;
        while (mask) {
            const int i = __ffsll((unsigned long long)mask) - 1;
            mask &= mask - 1;
            acc += kt[i][j];
        }
        const float y = 0.125f * acc;
        Y[roff + j] = (y >= 1.0f) ? 1.0f : 0.0f;
    }
}

// ============================== launch ======================================
extern "C" void kernel_launch(void* const* d_in, const int* in_sizes, int n_in,
                              void* d_out, int out_size, void* d_ws, size_t ws_size,
                              hipStream_t stream)
{
    const float* x        = (const float*)d_in[0];
    const float* q_w      = (const float*)d_in[1];
    const float* q_g      = (const float*)d_in[2];
    const float* q_b      = (const float*)d_in[3];
    const float* k_w      = (const float*)d_in[4];
    const float* k_g      = (const float*)d_in[5];
    const float* k_b      = (const float*)d_in[6];
    const float* v_w      = (const float*)d_in[7];
    const float* v_g      = (const float*)d_in[8];
    const float* v_b      = (const float*)d_in[9];
    const float* proj_w   = (const float*)d_in[10];
    const float* proj_bias= (const float*)d_in[11];
    const float* proj_g   = (const float*)d_in[12];
    const float* proj_beta= (const float*)d_in[13];
    const float* fc1_w    = (const float*)d_in[14];
    const float* fc1_bias = (const float*)d_in[15];
    const float* fc1_g    = (const float*)d_in[16];
    const float* fc1_beta = (const float*)d_in[17];
    const float* fc2_w    = (const float*)d_in[18];
    const float* fc2_bias = (const float*)d_in[19];
    const float* fc2_g    = (const float*)d_in[20];
    const float* fc2_beta = (const float*)d_in[21];

    const dim3 blk(256);
    const size_t NEEDED = 143654912;

    if (ws_size >= NEEDED) {
        char* ws = (char*)d_ws;
        float* U    = (float*)ws;
        float* Up2  = U + (size_t)NROWS * DIM;    // split-K partial 1 (z=1)
        u16*   Xsh  = (u16*)(ws + 67108864);
        u16*   Wbuf = (u16*)(ws + 100663296);
        u16*   Sq   = (u16*)(ws + 125829120);
        u16*   Sk   = (u16*)(ws + 134217728);
        u16*   SvYb = (u16*)((char*)Xsh + 25165824);
        u16*   Xs   = Xsh;          // [4096][3072]
        u16*   X1s  = Xsh;          // [4096][3072] (after Xs dead)
        u16*   Sm   = Xsh;          // [4096][4096] (after X1s dead)
        float* X1   = (float*)d_out;
        // ktv partials (4 MB) alias the Wbuf region (dead during attention)
        float* ktvp = (float*)(ws + 100663296);

        // 6-product exact fp32xfp32 plane pairs: (0,0)(1,1)(2,0)(0,2)(1,0)(0,1)
        const int pa6[6] = {0, 1, 2, 0, 1, 0}, pb6[6] = {0, 1, 0, 2, 0, 1};
        unsigned apack = 0, bpack = 0;
        for (int i = 0; i < 6; ++i) {
            apack |= (unsigned)pa6[i] << (4 * i);
            bpack |= (unsigned)pb6[i] << (4 * i);
        }
        SegList segP;  // spike x fp32, proj (K=1024/plane; Kseg=512, z in {0,1})
        {
            for (int i = 0; i < 6; ++i) { segP.a[i] = 0; segP.b[i] = 0; }
            segP.b[1] = 1024; segP.b[2] = 2048; segP.n = 3;
        }
        SegList segF2; // spike x fp32, fc2 (K=4096/plane; Kseg=2048, z in {0,1})
        {
            for (int i = 0; i < 6; ++i) { segF2.a[i] = 0; segF2.b[i] = 0; }
            segF2.b[1] = 4096; segF2.b[2] = 8192; segF2.n = 3;
        }

        split3_rows<<<dim3(1, NROWS), blk, 0, stream>>>(x, Xs, DIM);

        // merged q|k|v: Wt rows 0..1023 = q, 1024..2047 = k, 2048..3071 = v
        split_wt<<<dim3(16, 16), blk, 0, stream>>>(q_w, Wbuf,               DIM, DIM, 3072);
        split_wt<<<dim3(16, 16), blk, 0, stream>>>(k_w, Wbuf + 1024 * 3072, DIM, DIM, 3072);
        split_wt<<<dim3(16, 16), blk, 0, stream>>>(v_w, Wbuf + 2048 * 3072, DIM, DIM, 3072);
        gemm256<<<dim3(12, 16), dim3(512), 0, stream>>>(
            Xs, 3072, Wbuf, 3072, apack, bpack, 96, nullptr, U, 3072);
        lnlif2<DIM><<<NROWS, blk, 0, stream>>>(U, nullptr, 3072, 0,    q_g, q_b, nullptr, Sq,   nullptr, nullptr);
        lnlif2<DIM><<<NROWS, blk, 0, stream>>>(U, nullptr, 3072, 1024, k_g, k_b, nullptr, Sk,   nullptr, nullptr);
        lnlif2<DIM><<<NROWS, blk, 0, stream>>>(U, nullptr, 3072, 2048, v_g, v_b, nullptr, SvYb, nullptr, nullptr);

        // attention (exact): 4x partial ktv counts, then 0.125*q@ktv, LIF 0.5
        ktv_part<<<dim3(NB * NH, 4), blk, 0, stream>>>(Sk, SvYb, ktvp);
        qktv_bf16<<<dim3(NB * NH, 8), blk, 0, stream>>>(Sq, ktvp, SvYb);

        // proj (split-K x2) + LN + LIF; residual-1 into d_out (X1) + X1s planes
        split_wt<<<dim3(16, 16), blk, 0, stream>>>(proj_w, Wbuf, DIM, DIM, 3072);
        gemm_mfma<64><<<dim3(16, 32, 2), blk, 0, stream>>>(
            SvYb, 1024, Wbuf, 3072, segP, 512, proj_bias, U, DIM);
        lnlif2<DIM><<<NROWS, blk, 0, stream>>>(U, Up2, DIM, 0, proj_g, proj_beta, x, nullptr, X1, X1s);

        // fc1 + LN + LIF (spikes bf16 into Sm, overwrites X1s)
        split_wt<<<dim3(64, 16), blk, 0, stream>>>(fc1_w, Wbuf, DIM, HID, 3072);
        gemm256<<<dim3(16, 16), dim3(512), 0, stream>>>(
            X1s, 3072, Wbuf, 3072, apack, bpack, 96, fc1_bias, U, HID);
        lnlif2<HID><<<NROWS, blk, 0, stream>>>(U, nullptr, HID, 0, fc1_g, fc1_beta, nullptr, Sm, nullptr, nullptr);

        // fc2 (split-K x2) + LN + LIF + residual-2 -> d_out
        split_wt<<<dim3(16, 64), blk, 0, stream>>>(fc2_w, Wbuf, HID, DIM, 12288);
        gemm_mfma<64><<<dim3(16, 32, 2), blk, 0, stream>>>(
            Sm, 4096, Wbuf, 12288, segF2, 2048, fc2_bias, U, DIM);
        lnlif2<DIM><<<NROWS, blk, 0, stream>>>(U, Up2, DIM, 0, fc2_g, fc2_beta, X1, nullptr, (float*)d_out, nullptr);
        return;
    }

    // ---- fallback: round-2 fp32 path (verified; needs ~85 MB) ----
    float* U    = (float*)d_ws;
    float* Sq   = U + (size_t)1 * NROWS * DIM;
    float* Sk   = U + (size_t)2 * NROWS * DIM;
    float* Sv   = U + (size_t)3 * NROWS * DIM;
    float* Yb   = Sv;
    float* ktvb = U + (size_t)NROWS * HID;
    float* Y2   = ktvb + (size_t)NB * NH * HDIM * HDIM;
    float* X1   = (float*)d_out;
    float* outf = (float*)d_out;

    const dim3 gemm_d(DIM / BN, NROWS / BM);
    const dim3 gemm_h(HID / BN, NROWS / BM);

    gemm_f32<<<gemm_d, blk, 0, stream>>>(x, q_w, nullptr, U, NROWS, DIM, DIM);
    lnlif_old<DIM><<<NROWS, blk, 0, stream>>>(U, q_g, q_b, 2.0f, nullptr, Sq);
    gemm_f32<<<gemm_d, blk, 0, stream>>>(x, k_w, nullptr, U, NROWS, DIM, DIM);
    lnlif_old<DIM><<<NROWS, blk, 0, stream>>>(U, k_g, k_b, 2.0f, nullptr, Sk);
    gemm_f32<<<gemm_d, blk, 0, stream>>>(x, v_w, nullptr, U, NROWS, DIM, DIM);
    lnlif_old<DIM><<<NROWS, blk, 0, stream>>>(U, v_g, v_b, 2.0f, nullptr, Sv);

    ktv_f32<<<NB * NH, blk, 0, stream>>>(Sk, Sv, ktvb);
    qktv_f32<<<NB * NH, blk, 0, stream>>>(Sq, ktvb, Yb);

    gemm_f32<<<gemm_d, blk, 0, stream>>>(Yb, proj_w, proj_bias, U, NROWS, DIM, DIM);
    lnlif_old<DIM><<<NROWS, blk, 0, stream>>>(U, proj_g, proj_beta, 2.0f, x, X1);

    gemm_f32<<<gemm_h, blk, 0, stream>>>(X1, fc1_w, fc1_bias, U, NROWS, DIM, HID);
    lnlif_old<HID><<<NROWS, blk, 0, stream>>>(U, fc1_g, fc1_beta, 2.0f, nullptr, U);

    gemm_f32<<<gemm_d, blk, 0, stream>>>(U, fc2_w, fc2_bias, Y2, NROWS, HID, DIM);
    lnlif_old<DIM><<<NROWS, blk, 0, stream>>>(Y2, fc2_g, fc2_beta, 2.0f, X1, outf);
}